// Round 7
// baseline (30.229 us; speedup 1.0000x reference)
//
#include <hip/hip_runtime.h>

#define N_EXPERTS 8
#define ROWS_PB 8   // token rows per block
#define ENT_PB 16   // flat (token,k) assignments per block
typedef unsigned long long u64;
typedef float f32x4 __attribute__((ext_vector_type(4)));
typedef int i32x4 __attribute__((ext_vector_type(4)));

// Packed per-expert counts: experts 0-3 in c0, 4-7 in c1, 16-bit fields.
// Max per-field value: full prefix (<=32752) + block-local (<=16) < 65536.
__device__ __forceinline__ void packed_add(u64& c0, u64& c1, int e) {
  if (e < 4) c0 += 1ull << (16 * e);
  else       c1 += 1ull << (16 * (e - 4));
}
__device__ __forceinline__ void packed_add_val(u64& c0, u64& c1, int e, int v) {
  if (e < 4) c0 += (u64)v << (16 * e);
  else       c1 += (u64)v << (16 * (e - 4));
}
__device__ __forceinline__ int packed_get(u64 c0, u64 c1, int e) {
  return (e < 4) ? (int)((c0 >> (16 * e)) & 0xFFFF)
                 : (int)((c1 >> (16 * (e - 4))) & 0xFFFF);
}

// ---------------------------------------------------------------------------
// Kernel 1: per-superblock expert histograms. 32 blocks x 256 thr x int4.
// ---------------------------------------------------------------------------
__global__ __launch_bounds__(256) void hist_kernel(
    const int* __restrict__ te, int* __restrict__ hist) {
  __shared__ u64 w0s[4], w1s[4];
  const int tid = threadIdx.x;
  const int lane = tid & 63, wid = tid >> 6;
  const int g = blockIdx.x * 256 + tid;
  const i32x4 v = reinterpret_cast<const i32x4*>(te)[g];

  u64 c0 = 0, c1 = 0;
  packed_add(c0, c1, v.x & 7);
  packed_add(c0, c1, v.y & 7);
  packed_add(c0, c1, v.z & 7);
  packed_add(c0, c1, v.w & 7);
#pragma unroll
  for (int m = 1; m < 64; m <<= 1) {
    c0 += __shfl_xor(c0, m);
    c1 += __shfl_xor(c1, m);
  }
  if (lane == 0) { w0s[wid] = c0; w1s[wid] = c1; }
  __syncthreads();
  if (tid < N_EXPERTS) {
    int s = 0;
#pragma unroll
    for (int ww = 0; ww < 4; ++ww) s += packed_get(w0s[ww], w1s[ww], tid);
    hist[blockIdx.x * N_EXPERTS + tid] = s;
  }
}

// ---------------------------------------------------------------------------
// Kernel 2 (fused): identical structure to R4 (proven), plus non-temporal
// stores for `out` so the 64 MB write stream does not evict x from L3.
// ---------------------------------------------------------------------------
__global__ __launch_bounds__(256) void fused_kernel(
    const float* __restrict__ x, const int* __restrict__ te,
    const float* __restrict__ ew, const int* __restrict__ hist,
    const float* __restrict__ bias, float* __restrict__ out, int C) {
  __shared__ u64 w0s[4], w1s[4];
  __shared__ float scale_s[ROWS_PB];
  const int tid = threadIdx.x;
  const int lane = tid & 63, wid = tid >> 6;
  const int b = blockIdx.x;
  const int E0 = b * ENT_PB;          // first flat entry of this block
  const int sb = b >> 6;              // full superblocks (1024 entries each)
  const int partial4 = 4 * (b & 63);  // int4 count in the partial tail

  const i32x4* __restrict__ te4 = reinterpret_cast<const i32x4*>(te);

  // ---- prefetch the streaming data (issue loads early) ------------------
  const f32x4* __restrict__ x4 =
      reinterpret_cast<const f32x4*>(x) + b * (ROWS_PB * 256);
  f32x4 xv0 = x4[0 * 256 + tid];
  f32x4 xv1 = x4[1 * 256 + tid];
  f32x4 xv2 = x4[2 * 256 + tid];
  f32x4 xv3 = x4[3 * 256 + tid];
  f32x4 xv4 = x4[4 * 256 + tid];
  f32x4 xv5 = x4[5 * 256 + tid];
  f32x4 xv6 = x4[6 * 256 + tid];
  f32x4 xv7 = x4[7 * 256 + tid];
  const f32x4 bv = reinterpret_cast<const f32x4*>(bias)[tid];

  // ---- prologue: prefix counts (hist part + partial tail part) ----------
  u64 c0 = 0, c1 = 0;
  {
    const int bb = tid >> 3;          // superblock index for hist slot tid
    if (bb < sb) packed_add_val(c0, c1, tid & 7, hist[tid]);
  }
  if (tid < partial4) {
    const i32x4 v = te4[sb * 256 + tid];
    packed_add(c0, c1, v.x & 7);
    packed_add(c0, c1, v.y & 7);
    packed_add(c0, c1, v.z & 7);
    packed_add(c0, c1, v.w & 7);
  }
#pragma unroll
  for (int m = 1; m < 64; m <<= 1) {
    c0 += __shfl_xor(c0, m);
    c1 += __shfl_xor(c1, m);
  }
  if (lane == 0) { w0s[wid] = c0; w1s[wid] = c1; }
  __syncthreads();

  // ---- serial stable rank of this block's 16 entries --------------------
  if (tid == 0) {
    u64 p0 = w0s[0] + w0s[1] + w0s[2] + w0s[3];
    u64 p1 = w1s[0] + w1s[1] + w1s[2] + w1s[3];
    const f32x4* __restrict__ ew4 = reinterpret_cast<const f32x4*>(ew);
#pragma unroll
    for (int q = 0; q < 4; ++q) {
      const i32x4 v = te4[(E0 >> 2) + q];
      const f32x4 w = ew4[(E0 >> 2) + q];
      const int ee[4] = {v.x & 7, v.y & 7, v.z & 7, v.w & 7};
      const float wv[4] = {w.x, w.y, w.z, w.w};
      float s01 = 0.f, s23 = 0.f;
#pragma unroll
      for (int k = 0; k < 4; ++k) {
        const int e = ee[k];
        const int r = packed_get(p0, p1, e);
        packed_add(p0, p1, e);
        if (r < C) {
          if (k < 2) s01 += wv[k]; else s23 += wv[k];
        }
      }
      scale_s[q * 2 + 0] = s01;
      scale_s[q * 2 + 1] = s23;
    }
  }
  __syncthreads();

  // ---- stream: out = x * scale + bias (non-temporal stores) -------------
  f32x4* __restrict__ o4 = reinterpret_cast<f32x4*>(out) + b * (ROWS_PB * 256);
  {
    float s;
    f32x4 ov;
#define EMIT(K, XV)                                   \
    s = scale_s[K];                                   \
    ov = XV * s + bv;                                 \
    __builtin_nontemporal_store(ov, &o4[K * 256 + tid]);
    EMIT(0, xv0) EMIT(1, xv1) EMIT(2, xv2) EMIT(3, xv3)
    EMIT(4, xv4) EMIT(5, xv5) EMIT(6, xv6) EMIT(7, xv7)
#undef EMIT
  }
}

extern "C" void kernel_launch(void* const* d_in, const int* in_sizes, int n_in,
                              void* d_out, int out_size, void* d_ws,
                              size_t ws_size, hipStream_t stream) {
  // setup_inputs order: x, cond, mask, scores, expert_weights, top_experts, bias
  const float* x    = (const float*)d_in[0];
  const float* ew   = (const float*)d_in[4];
  const int*   te   = (const int*)d_in[5];
  const float* bias = (const float*)d_in[6];
  float* out = (float*)d_out;
  int* hist = (int*)d_ws;  // 256 ints

  const int T = in_sizes[5];       // 32768 flat assignments
  const int C = T / N_EXPERTS;     // 4096 expert capacity
  const int nblocks = (in_sizes[0] / 1024) / ROWS_PB;  // 2048

  hist_kernel<<<32, 256, 0, stream>>>(te, hist);
  fused_kernel<<<nblocks, 256, 0, stream>>>(x, te, ew, hist, bias, out, C);
}